// Round 1
// baseline (6241.925 us; speedup 1.0000x reference)
//
#include <hip/hip_runtime.h>
#include <stdint.h>

// Problem constants (ModalityTransformer): B=32, T=1024, d=512, dff=2048, H=8, N=4, L=2
#define BST    32768              // B*T
#define NMOD   4
#define MTOT   (NMOD*BST)         // 131072 rows for all GEMMs
#define DMODEL 512
#define DFF    2048
#define NH     8
#define HDIM   64
#define NLAYER 2
#define LNEPS  1e-5f

using half8 = __attribute__((ext_vector_type(8))) _Float16;
using half4 = __attribute__((ext_vector_type(4))) _Float16;
using f32x4 = __attribute__((ext_vector_type(4))) float;

// ---------------- fp32 -> fp16 convert (weights) ----------------
__global__ __launch_bounds__(256) void k_f32_to_f16(const float* __restrict__ src,
                                                    _Float16* __restrict__ dst, int n4) {
    int i = blockIdx.x * 256 + threadIdx.x;
    if (i >= n4) return;
    float4 v = ((const float4*)src)[i];
    half4 o = { (_Float16)v.x, (_Float16)v.y, (_Float16)v.z, (_Float16)v.w };
    ((half4*)dst)[i] = o;
}

// ---------------- concat 4x [BST, D] fp32 -> [4*BST, D] fp16 ----------------
__global__ __launch_bounds__(256) void k_concat4(const float* __restrict__ s0, const float* __restrict__ s1,
                                                 const float* __restrict__ s2, const float* __restrict__ s3,
                                                 _Float16* __restrict__ dst) {
    size_t i = (size_t)blockIdx.x * 256 + threadIdx.x;   // handles 4 elems
    size_t e = i * 4;
    int j = (int)(e >> 24);                              // BST*DMODEL = 2^24
    size_t rem = e & ((1u << 24) - 1);
    const float* s = (j == 0) ? s0 : (j == 1) ? s1 : (j == 2) ? s2 : s3;
    float4 v = *(const float4*)(s + rem);
    half4 o = { (_Float16)v.x, (_Float16)v.y, (_Float16)v.z, (_Float16)v.w };
    *(half4*)(dst + e) = o;
}

// ---------------- GEMM: C[M,F] = A[M,K] @ W[F,K]^T (+bias, opt ReLU), f16 in, f32 acc, f16 out
// 128x128 tile, BK=32, 256 threads (4 waves), each wave 64x64 (4x4 MFMA 16x16x32 tiles).
// Verified layouts (learn_hip m89/m91): A-frag A[m=lane&15][k=quad*8+j]; B-frag B[k=quad*8+j][n=lane&15];
// C/D: col=lane&15, row=quad*4+reg.
__global__ __launch_bounds__(256) void k_gemm_nt(const _Float16* __restrict__ A,
                                                 const _Float16* __restrict__ W,
                                                 const float* __restrict__ bias,
                                                 _Float16* __restrict__ C,
                                                 int K, int ldc, int relu) {
    __shared__ alignas(16) _Float16 As[128 * 32];
    __shared__ alignas(16) _Float16 Bs[128 * 32];
    const int tid  = threadIdx.x;
    const int lane = tid & 63;
    const int wv   = tid >> 6;        // 0..3
    const int quad = lane >> 4;       // 0..3
    const int lr   = lane & 15;
    const int wrow = (wv >> 1) * 64;
    const int wcol = (wv & 1) * 64;
    const size_t m0 = (size_t)blockIdx.x * 128;
    const size_t f0 = (size_t)blockIdx.y * 128;

    // staging: tile = 128 rows x 4 chunks(16B); thread does chunks tid and tid+256
    const int r0 = tid >> 2;          // 0..63
    const int c0 = tid & 3;
    const int r1 = r0 + 64;           // 64..127

    f32x4 acc[4][4] = {};

    const int nk = K >> 5;
    for (int kt = 0; kt < nk; ++kt) {
        const int kof = kt * 32;
        __syncthreads();
        uint4 a0 = *(const uint4*)(A + (m0 + r0) * (size_t)K + kof + c0 * 8);
        uint4 a1 = *(const uint4*)(A + (m0 + r1) * (size_t)K + kof + c0 * 8);
        uint4 b0 = *(const uint4*)(W + (f0 + r0) * (size_t)K + kof + c0 * 8);
        uint4 b1 = *(const uint4*)(W + (f0 + r1) * (size_t)K + kof + c0 * 8);
        *(uint4*)(As + r0 * 32 + c0 * 8) = a0;
        *(uint4*)(As + r1 * 32 + c0 * 8) = a1;
        *(uint4*)(Bs + r0 * 32 + c0 * 8) = b0;
        *(uint4*)(Bs + r1 * 32 + c0 * 8) = b1;
        __syncthreads();

        half8 af[4], bf[4];
#pragma unroll
        for (int mt = 0; mt < 4; ++mt)
            af[mt] = *(const half8*)(As + (wrow + mt * 16 + lr) * 32 + quad * 8);
#pragma unroll
        for (int nt = 0; nt < 4; ++nt)
            bf[nt] = *(const half8*)(Bs + (wcol + nt * 16 + lr) * 32 + quad * 8);
#pragma unroll
        for (int mt = 0; mt < 4; ++mt)
#pragma unroll
            for (int nt = 0; nt < 4; ++nt)
                acc[mt][nt] = __builtin_amdgcn_mfma_f32_16x16x32_f16(af[mt], bf[nt], acc[mt][nt], 0, 0, 0);
    }

#pragma unroll
    for (int mt = 0; mt < 4; ++mt) {
#pragma unroll
        for (int nt = 0; nt < 4; ++nt) {
            int col = (int)f0 + wcol + nt * 16 + lr;
            float bv = bias ? bias[col] : 0.0f;
#pragma unroll
            for (int r = 0; r < 4; ++r) {
                size_t row = m0 + wrow + mt * 16 + quad * 4 + r;
                float v = acc[mt][nt][r] + bv;
                if (relu) v = v > 0.0f ? v : 0.0f;
                C[row * (size_t)ldc + col] = (_Float16)v;
            }
        }
    }
}

// ---------------- attention core: per (bs, head): softmax(causal 4x4 scores) @ V ----------------
// grid = BST blocks x 256; wave w handles heads w and w+4; lane = hd index (64)
__global__ __launch_bounds__(256) void k_attn(const _Float16* __restrict__ Q,
                                              const _Float16* __restrict__ Kp,
                                              const _Float16* __restrict__ Vp,
                                              int ldq, _Float16* __restrict__ O, int ldo) {
    const int bs = blockIdx.x;
    const int tid = threadIdx.x;
    const int w = tid >> 6;
    const int c = tid & 63;
    for (int hh = 0; hh < 2; ++hh) {
        const int h = w + hh * 4;
        float qv[4], kv[4], vv[4];
#pragma unroll
        for (int i = 0; i < 4; ++i) {
            size_t off = ((size_t)(i * BST + bs)) * ldq + h * 64 + c;
            qv[i] = (float)Q[off];
            kv[i] = (float)Kp[off];
            vv[i] = (float)Vp[off];
        }
        float s[4][4];
#pragma unroll
        for (int i = 0; i < 4; ++i)
#pragma unroll
            for (int j = 0; j < 4; ++j) {
                if (j > i) continue;
                float p = qv[i] * kv[j];
#pragma unroll
                for (int off = 32; off >= 1; off >>= 1) p += __shfl_xor(p, off, 64);
                s[i][j] = p * 0.125f;   // 1/sqrt(64)
            }
#pragma unroll
        for (int i = 0; i < 4; ++i) {
            float mx = s[i][0];
            for (int j = 1; j <= i; ++j) mx = fmaxf(mx, s[i][j]);
            float e[4], sum = 0.0f;
            for (int j = 0; j <= i; ++j) { e[j] = __expf(s[i][j] - mx); sum += e[j]; }
            float inv = 1.0f / sum;
            float o = 0.0f;
            for (int j = 0; j <= i; ++j) o += e[j] * inv * vv[j];
            O[((size_t)(i * BST + bs)) * ldo + h * 64 + c] = (_Float16)o;
        }
    }
}

// ---------------- add + LayerNorm (row = 512). wave per row; lane c holds elems c+64*e ----------------
__global__ __launch_bounds__(256) void k_add_ln(const _Float16* __restrict__ X,
                                                const _Float16* __restrict__ Y,
                                                const float* __restrict__ g,
                                                const float* __restrict__ b,
                                                _Float16* __restrict__ out16,
                                                float* __restrict__ out32) {
    const int tid = threadIdx.x;
    const int w = tid >> 6, c = tid & 63;
    const size_t m = (size_t)blockIdx.x * 4 + w;
    const size_t base = m * DMODEL;
    float v[8];
    float sum = 0.0f;
#pragma unroll
    for (int e = 0; e < 8; ++e) {
        int idx = e * 64 + c;
        v[e] = (float)X[base + idx] + (float)Y[base + idx];
        sum += v[e];
    }
#pragma unroll
    for (int off = 32; off >= 1; off >>= 1) sum += __shfl_xor(sum, off, 64);
    const float mu = sum * (1.0f / 512.0f);
    float vs = 0.0f;
#pragma unroll
    for (int e = 0; e < 8; ++e) { float d = v[e] - mu; vs += d * d; }
#pragma unroll
    for (int off = 32; off >= 1; off >>= 1) vs += __shfl_xor(vs, off, 64);
    const float rs = rsqrtf(vs * (1.0f / 512.0f) + LNEPS);
#pragma unroll
    for (int e = 0; e < 8; ++e) {
        int idx = e * 64 + c;
        float o = (v[e] - mu) * rs * g[idx] + b[idx];
        if (out32) out32[base + idx] = o;
        else       out16[base + idx] = (_Float16)o;
    }
}

extern "C" void kernel_launch(void* const* d_in, const int* in_sizes, int n_in,
                              void* d_out, int out_size, void* d_ws, size_t ws_size,
                              hipStream_t stream) {
    const float* ctx0       = (const float*)d_in[0];
    const float* ctx1       = (const float*)d_in[1];
    const float* ctx2       = (const float*)d_in[2];
    const float* h_ctx      = (const float*)d_in[3];
    const float* h_tgt0     = (const float*)d_in[4];
    const float* h_tgt1     = (const float*)d_in[5];
    const float* h_tgt2     = (const float*)d_in[6];
    const float* h_tgt3     = (const float*)d_in[7];
    const float* Wqkv_self  = (const float*)d_in[8];
    const float* bqkv_self  = (const float*)d_in[9];
    const float* Wo_self    = (const float*)d_in[10];
    const float* bo_self    = (const float*)d_in[11];
    const float* Wqkv_cross = (const float*)d_in[12];
    const float* bqkv_cross = (const float*)d_in[13];
    const float* Wo_cross   = (const float*)d_in[14];
    const float* bo_cross   = (const float*)d_in[15];
    const float* W1         = (const float*)d_in[16];
    const float* b1         = (const float*)d_in[17];
    const float* W2         = (const float*)d_in[18];
    const float* b2         = (const float*)d_in[19];
    const float* ln_g       = (const float*)d_in[20];
    const float* ln_b       = (const float*)d_in[21];

    char* wsb = (char*)d_ws;
    size_t off = 0;
    auto carve = [&](size_t bytes) -> void* {
        void* p = wsb + off;
        off += (bytes + 255) & ~(size_t)255;
        return p;
    };
    _Float16* x     = (_Float16*)carve((size_t)MTOT * DMODEL * 2);
    _Float16* memb  = (_Float16*)carve((size_t)MTOT * DMODEL * 2);
    _Float16* big   = (_Float16*)carve((size_t)MTOT * DFF * 2);     // qkv (M x 1536) + attno (M x 512)
    _Float16* projo = (_Float16*)carve((size_t)MTOT * DMODEL * 2);
    _Float16* wqs = (_Float16*)carve((size_t)NLAYER * 3 * DMODEL * DMODEL * 2);
    _Float16* wos = (_Float16*)carve((size_t)NLAYER * DMODEL * DMODEL * 2);
    _Float16* wqc = (_Float16*)carve((size_t)NLAYER * 3 * DMODEL * DMODEL * 2);
    _Float16* woc = (_Float16*)carve((size_t)NLAYER * DMODEL * DMODEL * 2);
    _Float16* w1h = (_Float16*)carve((size_t)NLAYER * DFF * DMODEL * 2);
    _Float16* w2h = (_Float16*)carve((size_t)NLAYER * DMODEL * DFF * 2);
    _Float16* attno = big + (size_t)MTOT * 1536;

    auto conv = [&](const float* s, _Float16* dst, int n) {
        int n4 = n / 4;
        k_f32_to_f16<<<(n4 + 255) / 256, 256, 0, stream>>>(s, dst, n4);
    };
    conv(Wqkv_self,  wqs, NLAYER * 3 * DMODEL * DMODEL);
    conv(Wo_self,    wos, NLAYER * DMODEL * DMODEL);
    conv(Wqkv_cross, wqc, NLAYER * 3 * DMODEL * DMODEL);
    conv(Wo_cross,   woc, NLAYER * DMODEL * DMODEL);
    conv(W1,         w1h, NLAYER * DFF * DMODEL);
    conv(W2,         w2h, NLAYER * DMODEL * DFF);

    const int concat_blocks = (MTOT * DMODEL / 4) / 256;   // 65536
    k_concat4<<<concat_blocks, 256, 0, stream>>>(h_tgt0, h_tgt1, h_tgt2, h_tgt3, x);
    k_concat4<<<concat_blocks, 256, 0, stream>>>(h_ctx, ctx0, ctx1, ctx2, memb);

    auto gemm = [&](const _Float16* A, const _Float16* Wp, const float* bias, _Float16* Cc,
                    int K, int F, int ldc, int relu) {
        dim3 g(MTOT / 128, F / 128);
        k_gemm_nt<<<g, 256, 0, stream>>>(A, Wp, bias, Cc, K, ldc, relu);
    };

    for (int l = 0; l < NLAYER; ++l) {
        // ---- self attention ----
        gemm(x, wqs + (size_t)l * 3 * DMODEL * DMODEL, bqkv_self + l * 3 * DMODEL,
             big, DMODEL, 3 * DMODEL, 3 * DMODEL, 0);
        k_attn<<<BST, 256, 0, stream>>>(big, big + 512, big + 1024, 3 * DMODEL, attno, DMODEL);
        gemm(attno, wos + (size_t)l * DMODEL * DMODEL, bo_self + l * DMODEL,
             projo, DMODEL, DMODEL, DMODEL, 0);
        k_add_ln<<<MTOT / 4, 256, 0, stream>>>(x, projo, ln_g + (l * 3 + 0) * DMODEL,
                                               ln_b + (l * 3 + 0) * DMODEL, x, nullptr);
        // ---- cross attention ----
        const _Float16* Wc = wqc + (size_t)l * 3 * DMODEL * DMODEL;
        gemm(x, Wc, bqkv_cross + l * 3 * DMODEL, big, DMODEL, DMODEL, 3 * DMODEL, 0);          // Q
        gemm(memb, Wc + (size_t)DMODEL * DMODEL, bqkv_cross + l * 3 * DMODEL + DMODEL,
             big + 512, DMODEL, 2 * DMODEL, 3 * DMODEL, 0);                                     // K,V
        k_attn<<<BST, 256, 0, stream>>>(big, big + 512, big + 1024, 3 * DMODEL, attno, DMODEL);
        gemm(attno, woc + (size_t)l * DMODEL * DMODEL, bo_cross + l * DMODEL,
             projo, DMODEL, DMODEL, DMODEL, 0);
        k_add_ln<<<MTOT / 4, 256, 0, stream>>>(x, projo, ln_g + (l * 3 + 1) * DMODEL,
                                               ln_b + (l * 3 + 1) * DMODEL, x, nullptr);
        // ---- FFN ----
        gemm(x, w1h + (size_t)l * DFF * DMODEL, b1 + l * DFF, big, DMODEL, DFF, DFF, 1);
        gemm(big, w2h + (size_t)l * DMODEL * DFF, b2 + l * DMODEL, projo, DFF, DMODEL, DMODEL, 0);
        const bool last = (l == NLAYER - 1);
        k_add_ln<<<MTOT / 4, 256, 0, stream>>>(x, projo, ln_g + (l * 3 + 2) * DMODEL,
                                               ln_b + (l * 3 + 2) * DMODEL,
                                               last ? nullptr : x, last ? (float*)d_out : nullptr);
    }
    (void)in_sizes; (void)n_in; (void)out_size; (void)ws_size;
}